// Round 8
// baseline (7378.645 us; speedup 1.0000x reference)
//
#include <hip/hip_runtime.h>
#include <cstdint>
#include <cstddef>

typedef unsigned int   u32;
typedef unsigned short u16;
typedef unsigned long long u64;
typedef __attribute__((ext_vector_type(8))) short bf16x8;   // 8 bf16 = 4 VGPR
typedef __attribute__((ext_vector_type(4))) float f32x4;

#define B_  512
#define T_  168
#define H_  512

// ---------------- workspace layout (bytes). Requires ws_size >= 16MB + 8KB ----
#define OFF_U1P   (0u)                    // packed U1   bf16 [16kc][128ng][64][8]  (2MB)
#define OFF_UW2P  (2u*1024*1024)          // packed W2;U2 bf16 [32kc][128ng][64][8] (4MB)
#define OFF_H1    (6u*1024*1024)          // h1 ring, 8 slots x 512KB
#define OFF_H2    (14u*1024*1024)         // h2 ring, 2 slots x 512KB
#define OFF_FLAGS (16u*1024*1024)         // done counters (256B stride)
#define H_SLOT    262144u                 // u16 elems per slot = 32bg*16kc*64*8
#define NRING     8
#define FSTRIDE   64                      // ints per flag slot (256B)
// v8 uniform LDS per block: B(64K) + hlds(6K) + wlds(1.5K) -> 72KB => 2 blocks/CU
#define SMEM_V8   (65536 + 6144 + 2048)

__device__ __forceinline__ u16 f2bf(float v){              // RNE f32->bf16
  u32 u = __float_as_uint(v);
  return (u16)((u + 0x7fffu + ((u >> 16) & 1u)) >> 16);
}
__device__ __forceinline__ float sigm_f(float x){ return __fdividef(1.f, 1.f + __expf(-x)); }
__device__ __forceinline__ float tanh_ff(float x){
  float e = __expf(-2.f*fabsf(x));
  float t = __fdividef(1.f - e, 1.f + e);
  return (x < 0.f) ? -t : t;
}
// Memory model (r1-r7 lessons):
//  - polls: relaxed sc1 atomic loads (no cache maintenance while spinning)
//  - ring STORES: relaxed sc1 (direct to LLC; SYSTEM scope would write through to HBM)
//  - ring LOADS: plain cached; freshness from one per-wave agent-acquire fence
//    (buffer_inv) after spin success -> same-XCD readers share the L2 fill
//    (r7: FETCH 1.03GB -> 0.22GB).
//  - release: workgroup-release fence (drains own vmcnt; sc1 stores then complete
//    at LLC = agent coherence point) + relaxed agent RMW.
__device__ __forceinline__ void spin_ge(int* p, int target){
  while (__hip_atomic_load(p, __ATOMIC_RELAXED, __HIP_MEMORY_SCOPE_AGENT) < target)
    __builtin_amdgcn_s_sleep(1);
}
__device__ __forceinline__ void async_cp16(const void* g, void* l){
  __builtin_amdgcn_global_load_lds((const __attribute__((address_space(1))) u32*)g,
                                   (__attribute__((address_space(3))) u32*)l, 16, 0, 0);
}
__device__ __forceinline__ bf16x8 plain_ld16(const u16* p){ return *(const bf16x8*)p; }
__device__ __forceinline__ void ring_st16(u16* p, uint4 v){
  u64 lo = ((u64)v.y << 32) | v.x;
  u64 hi = ((u64)v.w << 32) | v.z;
  __hip_atomic_store((u64*)p,     lo, __ATOMIC_RELAXED, __HIP_MEMORY_SCOPE_AGENT);
  __hip_atomic_store(((u64*)p)+1, hi, __ATOMIC_RELAXED, __HIP_MEMORY_SCOPE_AGENT);
}

// ---------------- weight packing: B-operand fragment layout ------------------
// dst[((kc*128+ng)*64+ln)*8+j] = U[kc*32 + (ln>>4)*8 + j][ng*16 + (ln&15)]
__global__ void pack_w_kernel(const float* __restrict__ U1, const float* __restrict__ W2,
                              const float* __restrict__ U2, u16* __restrict__ U1p,
                              u16* __restrict__ UW2p)
{
  int idx = blockIdx.x*256 + threadIdx.x;
  int ln = idx & 63;
  int q8 = ((ln >> 4) << 3);
  int cl = ln & 15;
  if (idx < 16*128*64) {
    int kc = idx >> 13, ng = (idx >> 6) & 127;
    int row0 = kc*32 + q8, col = ng*16 + cl;
    u16* d = U1p + (size_t)idx*8;
    #pragma unroll
    for (int j=0;j<8;j++) d[j] = f2bf(U1[(size_t)(row0+j)*2048 + col]);
  } else {
    int i2 = idx - 16*128*64;
    if (i2 >= 32*128*64) return;
    int kc = i2 >> 13, ng = (i2 >> 6) & 127;
    int row0 = kc*32 + q8, col = ng*16 + cl;
    u16* d = UW2p + (size_t)i2*8;
    #pragma unroll
    for (int j=0;j<8;j++){
      int r = row0 + j;
      float v = (r < 512) ? W2[(size_t)r*2048 + col] : U2[(size_t)(r-512)*2048 + col];
      d[j] = f2bf(v);
    }
  }
}

__global__ void init_kernel(float* __restrict__ out, const float* __restrict__ fcb,
                            int* __restrict__ flags)
{
  int i = blockIdx.x*256 + threadIdx.x;
  if (i < 2048) flags[i] = 0;
  if (i < B_*T_) out[i] = fcb[0];
}

// ================================ v8 =========================================
// 384 blocks, uniform 72KB LDS -> guaranteed 2 blocks/CU co-residency (latency
// of one block's handshake hidden by partner's compute). Wave-autonomous steps:
// zero per-step __syncthreads (hlds/pack are wave-disjoint); per-wave spin +
// acquire fence + release fence + flag RMW (+1 each; targets are x4 waves).
//
// L1: blk 0..255:  bi = blk&7 (8 cohorts x 64 rows), hj = blk>>3 (0..31, 16 cols)
//     cohort = 32 blocks on one XCD (blk%8 heuristic) -> shared h1 L2 fills.
//     B (U1 slice, K=512 x 16cols x 4gates) = 64KB LDS, staged once.
// L2: blk 256..383: xcd=i&7, bi2=xcd>>1 (4 cohorts x 128 rows), hj=(i>>3)+(xcd&1)*16
//     U2 (recurrent) half in 64KB LDS; W2 (h1) half streamed global->VGPR per
//     wave (immutable weights, plain cached loads, no barriers).
//     Split-spin: h1-half GEMM runs BEFORE the done2 spin (L1 runs ~8 steps
//     ahead so h1[t] is ready early) -> only the h2-half sits on the
//     self-recurrence critical path.

__device__ void run_l1_v8(char* smem, int blk, const float* __restrict__ inp,
                          const float* __restrict__ W1, const float* __restrict__ V,
                          const float* __restrict__ bias, char* __restrict__ ws)
{
  u16*  Bl   = (u16*)smem;                       // [16kc][4gate][512]
  u16*  hlds = (u16*)(smem + 65536);             // 64 x 24
  float* wlds = (float*)(smem + 65536 + 6144);   // 4*16*6
  constexpr int RS = 24;
  const int tid = threadIdx.x, w = tid>>6, ln = tid&63, col = ln&15, quad = ln>>4;
  const int bi = blk & 7, hj = blk >> 3, h0 = hj*16, bg = bi*4 + w;

  const u16* Upak = (const u16*)(ws + OFF_U1P);
  const u16* H1r  = (const u16*)(ws + OFF_H1);
  u16* Hw = (u16*)(ws + OFF_H1);
  int* done1 = (int*)(ws + OFF_FLAGS) + bi*FSTRIDE;
  int* done2 = (int*)(ws + OFF_FLAGS) + 1024 + (bi>>1)*FSTRIDE;

  // stage B once: 64 pieces x 1KB, 16/wave
  #pragma unroll
  for (int p=0;p<16;p++){
    int pid = w*16 + p, kc = pid>>2, g = pid&3;
    int ng = g*32 + hj;
    async_cp16(Upak + ((size_t)(kc*128+ng)*64 + ln)*8, Bl + (size_t)pid*512);
  }
  for (int idx=tid; idx<4*16*6; idx+=256){
    int gate = idx/96, rem = idx%96, hcol = rem/6, k = rem%6;
    int gcol = gate*512 + h0 + hcol;
    wlds[idx] = (k==0)? bias[gcol] : (k<=4 ? V[(size_t)(k-1)*2048 + gcol] : W1[gcol]);
  }

  float c[4];
  #pragma unroll
  for (int i=0;i<4;i++) c[i] = 0.f;
  const f32x4 vzero = {0.f,0.f,0.f,0.f};
  __syncthreads();   // the ONLY block barrier: B-stage + wlds visible

  for (int t=0; t<T_; t++){
    if (t > 0){
      if (ln == 0){
        spin_ge(done1, 128*t);                          // cohort: h1[t-1] full-K ready
        if (t >= NRING) spin_ge(done2, 128*(t-NRING+1));// h1 ring back-pressure (L2 readers)
      }
      __builtin_amdgcn_fence(__ATOMIC_ACQUIRE, "agent"); // per-wave buffer_inv
    }

    f32x4 acc[4];
    #pragma unroll
    for (int i=0;i<4;i++) acc[i] = vzero;

    if (t > 0){
      const u16* ab = H1r + (size_t)((t-1)&7)*H_SLOT + (size_t)bg*16*512 + (size_t)ln*8;
      bf16x8 aw[8];
      #pragma unroll
      for (int i=0;i<8;i++) aw[i] = plain_ld16(ab + (size_t)i*512);
      #pragma unroll
      for (int kc=0; kc<16; kc++){
        bf16x8 av = aw[kc&7];
        if (kc < 8) aw[kc&7] = plain_ld16(ab + (size_t)(kc+8)*512);
        const u16* bb = Bl + (size_t)kc*4*512 + (size_t)ln*8;
        #pragma unroll
        for (int g=0; g<4; g++)
          acc[g] = __builtin_amdgcn_mfma_f32_16x16x32_bf16(
              av, *(const bf16x8*)(bb + (size_t)g*512), acc[g], 0,0,0);
      }
    }

    // epilogue (wave-local, 16 cols -> single h-group)
    float wv[4][6];
    #pragma unroll
    for (int gate=0; gate<4; gate++){
      const float* wp = wlds + (size_t)(gate*16 + col)*6;
      #pragma unroll
      for (int k=0;k<6;k++) wv[gate][k] = wp[k];
    }
    #pragma unroll
    for (int r=0;r<4;r++){
      const float* ip = inp + ((size_t)(bi*64 + w*16 + quad*4 + r)*T_ + t)*5;
      float i0=ip[0], i1=ip[1], i2=ip[2], i3=ip[3], i4=ip[4];
      float gv[4];
      #pragma unroll
      for (int gate=0; gate<4; gate++){
        gv[gate] = acc[gate][r] + wv[gate][0]
                 + i0*wv[gate][1] + i1*wv[gate][2] + i2*wv[gate][3] + i3*wv[gate][4]
                 + i4*wv[gate][5];
      }
      float ig=sigm_f(gv[0]), fg=sigm_f(gv[1]), gg=tanh_ff(gv[2]), og=sigm_f(gv[3]);
      float cn = fg*c[r] + ig*gg;
      c[r] = cn;
      hlds[(size_t)(w*16 + quad*4 + r)*RS + col] = f2bf(og*tanh_ff(cn));
    }
    // pack (same-wave transpose; 32 active lanes); 16 cols = half a kc tile
    if (ln < 32){
      int m = ln & 15, ch = (ln >> 4) & 1;
      uint4 v = *(const uint4*)&hlds[(size_t)(w*16 + m)*RS + ch*8];
      int lp = ((hj&1)*2 + ch)*16 + m;
      ring_st16(Hw + (size_t)(t&7)*H_SLOT + (((size_t)bg*16 + (hj>>1))*64 + lp)*8, v);
    }
    __builtin_amdgcn_fence(__ATOMIC_RELEASE, "workgroup");  // drain own vmcnt
    if (ln == 0)
      __hip_atomic_fetch_add(done1, 1, __ATOMIC_RELAXED, __HIP_MEMORY_SCOPE_AGENT);
  }
}

__device__ void run_l2_v8(char* smem, int i, const float* __restrict__ inp,
                          const float* __restrict__ V, const float* __restrict__ bias,
                          const float* __restrict__ fcw, char* __restrict__ ws,
                          float* __restrict__ out)
{
  u16*  Bl   = (u16*)smem;                       // U2 half: [16kc][4gate][512]
  u16*  hlds = (u16*)(smem + 65536);             // 128 x 24
  float* wlds = (float*)(smem + 65536 + 6144);   // 4*16*6
  constexpr int RS = 24;
  const int tid = threadIdx.x, w = tid>>6, ln = tid&63, col = ln&15, quad = ln>>4;
  const int xcd = i & 7, bi2 = xcd >> 1, hj = (i >> 3) + (xcd & 1)*16;
  const int h0 = hj*16;
  const int bgA = bi2*8 + w, bgB = bgA + 4;

  const u16* Upak = (const u16*)(ws + OFF_UW2P);
  const u16* H1r  = (const u16*)(ws + OFF_H1);
  const u16* H2r  = (const u16*)(ws + OFF_H2);
  u16* Hw = (u16*)(ws + OFF_H2);
  int* flags = (int*)(ws + OFF_FLAGS);
  int* d1a = flags + (2*bi2)*FSTRIDE;
  int* d1b = flags + (2*bi2+1)*FSTRIDE;
  int* done2 = flags + 1024 + bi2*FSTRIDE;

  // stage recurrent (U2) half of B once: kc' = 16+kc in packed UW2P
  #pragma unroll
  for (int p=0;p<16;p++){
    int pid = w*16 + p, kc = pid>>2, g = pid&3;
    int ng = g*32 + hj;
    async_cp16(Upak + ((size_t)((16+kc)*128+ng)*64 + ln)*8, Bl + (size_t)pid*512);
  }
  for (int idx=tid; idx<4*16*6; idx+=256){
    int gate = idx/96, rem = idx%96, hcol = rem/6, k = rem%6;
    int gcol = gate*512 + h0 + hcol;
    wlds[idx] = (k==0)? bias[gcol] : (k<=4 ? V[(size_t)(k-1)*2048 + gcol] : 0.f);
  }
  const float fcwr = fcw[h0 + col];

  float c[8];
  #pragma unroll
  for (int i2_=0;i2_<8;i2_++) c[i2_] = 0.f;
  const f32x4 vzero = {0.f,0.f,0.f,0.f};
  __syncthreads();   // the ONLY block barrier

  for (int t=0; t<T_; t++){
    // ---- phase 1: h1-half (ready early; off the self-recurrence path) -------
    if (ln == 0){ spin_ge(d1a, 128*(t+1)); spin_ge(d1b, 128*(t+1)); }
    __builtin_amdgcn_fence(__ATOMIC_ACQUIRE, "agent");

    f32x4 accA[4], accB[4];
    #pragma unroll
    for (int q=0;q<4;q++){ accA[q] = vzero; accB[q] = vzero; }

    {
      const u16* A1 = H1r + (size_t)(t&7)*H_SLOT;
      #pragma unroll
      for (int kc=0; kc<16; kc++){
        bf16x8 avA = plain_ld16(A1 + ((size_t)bgA*16 + kc)*512 + (size_t)ln*8);
        bf16x8 avB = plain_ld16(A1 + ((size_t)bgB*16 + kc)*512 + (size_t)ln*8);
        #pragma unroll
        for (int g=0; g<4; g++){
          bf16x8 bf = plain_ld16(Upak + ((size_t)(kc*128 + g*32 + hj)*64 + ln)*8);
          accA[g] = __builtin_amdgcn_mfma_f32_16x16x32_bf16(avA, bf, accA[g], 0,0,0);
          accB[g] = __builtin_amdgcn_mfma_f32_16x16x32_bf16(avB, bf, accB[g], 0,0,0);
        }
      }
    }

    // ---- phase 2: h2-half (the recurrence critical path) --------------------
    if (t > 0){
      if (ln == 0) spin_ge(done2, 128*t);
      __builtin_amdgcn_fence(__ATOMIC_ACQUIRE, "agent");
      const u16* A2 = H2r + (size_t)((t-1)&1)*H_SLOT;
      #pragma unroll
      for (int kc=0; kc<16; kc++){
        bf16x8 avA = plain_ld16(A2 + ((size_t)bgA*16 + kc)*512 + (size_t)ln*8);
        bf16x8 avB = plain_ld16(A2 + ((size_t)bgB*16 + kc)*512 + (size_t)ln*8);
        const u16* bb = Bl + (size_t)kc*4*512 + (size_t)ln*8;
        #pragma unroll
        for (int g=0; g<4; g++){
          bf16x8 bf = *(const bf16x8*)(bb + (size_t)g*512);
          accA[g] = __builtin_amdgcn_mfma_f32_16x16x32_bf16(avA, bf, accA[g], 0,0,0);
          accB[g] = __builtin_amdgcn_mfma_f32_16x16x32_bf16(avB, bf, accB[g], 0,0,0);
        }
      }
    }

    // ---- epilogue (wave-local) ----------------------------------------------
    float wv[4][5];
    #pragma unroll
    for (int gate=0; gate<4; gate++){
      const float* wp = wlds + (size_t)(gate*16 + col)*6;
      #pragma unroll
      for (int k=0;k<5;k++) wv[gate][k] = wp[k];
    }
    float fcp[2][4];
    #pragma unroll
    for (int sel=0; sel<2; sel++){
      const f32x4* ac = sel ? accB : accA;
      #pragma unroll
      for (int r=0;r<4;r++){
        const float* ip = inp + ((size_t)(bi2*128 + sel*64 + w*16 + quad*4 + r)*T_ + t)*5;
        float i0=ip[0], i1=ip[1], i2=ip[2], i3=ip[3];
        float gv[4];
        #pragma unroll
        for (int gate=0; gate<4; gate++){
          gv[gate] = ac[gate][r] + wv[gate][0]
                   + i0*wv[gate][1] + i1*wv[gate][2] + i2*wv[gate][3] + i3*wv[gate][4];
        }
        float ig=sigm_f(gv[0]), fg=sigm_f(gv[1]), gg=tanh_ff(gv[2]), og=sigm_f(gv[3]);
        float cn = fg*c[sel*4+r] + ig*gg;
        c[sel*4+r] = cn;
        float h = og*tanh_ff(cn);
        fcp[sel][r] = h*fcwr;
        hlds[(size_t)(sel*64 + w*16 + quad*4 + r)*RS + col] = f2bf(h);
      }
    }
    #pragma unroll
    for (int sel=0; sel<2; sel++){
      #pragma unroll
      for (int r=0;r<4;r++){
        float v = fcp[sel][r];
        #pragma unroll
        for (int m=1;m<16;m<<=1) v += __shfl_xor(v, m, 16);
        if (col == 0)
          atomicAdd(&out[(size_t)(bi2*128 + sel*64 + w*16 + quad*4 + r)*T_ + t], v);
      }
    }
    // pack: same-wave transpose; 64 active lanes (sel via ln>>5)
    {
      int sel = ln>>5, ch = (ln>>4)&1, m = ln&15;
      uint4 v = *(const uint4*)&hlds[(size_t)(sel*64 + w*16 + m)*RS + ch*8];
      int lp = ((hj&1)*2 + ch)*16 + m;
      int bgx = bi2*8 + sel*4 + w;
      ring_st16(Hw + (size_t)(t&1)*H_SLOT + (((size_t)bgx*16 + (hj>>1))*64 + lp)*8, v);
    }
    __builtin_amdgcn_fence(__ATOMIC_RELEASE, "workgroup");
    if (ln == 0)
      __hip_atomic_fetch_add(done2, 1, __ATOMIC_RELAXED, __HIP_MEMORY_SCOPE_AGENT);
  }
}

__global__ void __launch_bounds__(256, 2)
lstm_main_v8(const float* __restrict__ inp, const float* __restrict__ W1,
             const float* __restrict__ V1, const float* __restrict__ b1,
             const float* __restrict__ V2, const float* __restrict__ b2,
             const float* __restrict__ fcw, char* __restrict__ ws, float* __restrict__ out)
{
  extern __shared__ char smem[];
  int blk = blockIdx.x;
  if (blk < 256) run_l1_v8(smem, blk, inp, W1, V1, b1, ws);
  else           run_l2_v8(smem, blk-256, inp, V2, b2, fcw, ws, out);
}

extern "C" void kernel_launch(void* const* d_in, const int* in_sizes, int n_in,
                              void* d_out, int out_size, void* d_ws, size_t ws_size,
                              hipStream_t stream) {
  const float* inp = (const float*)d_in[0];
  const float* W1  = (const float*)d_in[1];
  const float* U1  = (const float*)d_in[2];
  const float* V1  = (const float*)d_in[3];
  const float* b1  = (const float*)d_in[4];
  const float* W2  = (const float*)d_in[5];
  const float* U2  = (const float*)d_in[6];
  const float* V2  = (const float*)d_in[7];
  const float* b2  = (const float*)d_in[8];
  const float* fcw = (const float*)d_in[9];
  const float* fcb = (const float*)d_in[10];
  char* ws = (char*)d_ws;
  float* out = (float*)d_out;

  pack_w_kernel<<<1536, 256, 0, stream>>>(U1, W2, U2,
      (u16*)(ws + OFF_U1P), (u16*)(ws + OFF_UW2P));
  init_kernel<<<(B_*T_ + 255)/256, 256, 0, stream>>>(out, fcb, (int*)(ws + OFF_FLAGS));

  // 384 blocks x 72KB uniform LDS: capacity is 2 blocks/CU x 256 CUs = 512 >=
  // 384, so full co-residency is guaranteed for any block->CU mapping (no
  // mixed-footprint placement hazard), and spin-flag sync is safe.
  (void)hipFuncSetAttribute((const void*)lstm_main_v8,
                            hipFuncAttributeMaxDynamicSharedMemorySize, SMEM_V8);
  lstm_main_v8<<<384, 256, SMEM_V8, stream>>>(inp, W1, V1, b1, V2, b2, fcw, ws, out);
}

// Round 9
// 2495.420 us; speedup vs baseline: 2.9569x; 2.9569x over previous
//
#include <hip/hip_runtime.h>
#include <cstdint>
#include <cstddef>

typedef unsigned int   u32;
typedef unsigned short u16;
typedef unsigned long long u64;
typedef __attribute__((ext_vector_type(8))) short bf16x8;   // 8 bf16 = 4 VGPR
typedef __attribute__((ext_vector_type(4))) float f32x4;

#define B_  512
#define T_  168
#define H_  512

// ---------------- workspace layout (bytes). Requires ws_size >= 16MB + 8KB ----
#define OFF_U1P   (0u)                    // packed U1   bf16 [16kc][128ng][64][8]  (2MB)
#define OFF_UW2P  (2u*1024*1024)          // packed W2;U2 bf16 [32kc][128ng][64][8] (4MB)
#define OFF_H1    (6u*1024*1024)          // h1 ring, 8 slots x 512KB
#define OFF_H2    (14u*1024*1024)         // h2 ring, 2 slots x 512KB
#define OFF_FLAGS (16u*1024*1024)         // done counters (256B stride)
#define H_SLOT    262144u                 // u16 elems per slot = 32bg*16kc*64*8
#define NRING     8
#define FSTRIDE   64                      // ints per flag slot (256B)
#define SMEM_V9   (131072 + 6144 + 3072)  // B(128K) + hlds(6K) + wlds(3K)

__device__ __forceinline__ u16 f2bf(float v){              // RNE f32->bf16
  u32 u = __float_as_uint(v);
  return (u16)((u + 0x7fffu + ((u >> 16) & 1u)) >> 16);
}
__device__ __forceinline__ float sigm_f(float x){ return __fdividef(1.f, 1.f + __expf(-x)); }
__device__ __forceinline__ float tanh_ff(float x){
  float e = __expf(-2.f*fabsf(x));
  float t = __fdividef(1.f - e, 1.f + e);
  return (x < 0.f) ? -t : t;
}
// Memory model (r1-r8 lessons, v7-proven):
//  - polls: relaxed sc1 atomic loads (no cache maintenance while spinning)
//  - ring STORES: relaxed sc1 (LLC write-back; SYSTEM scope = HBM write-through)
//  - ring LOADS: plain cached; freshness from block-level (tid0) agent-acquire
//    fence (buffer_inv) + __syncthreads broadcast -> same-XCD cohort shares the
//    L2 fill (r7: FETCH 1.03GB -> 0.22GB).
//  - release: workgroup-release fence (drains vmcnt; sc1 stores complete at LLC)
//    + relaxed agent RMW by tid0.
//  - RULE (r8): nothing may rely on cross-step L2 residency (per-step inv wipes
//    it) -> all weights live in LDS.
__device__ __forceinline__ void spin_ge(int* p, int target){
  while (__hip_atomic_load(p, __ATOMIC_RELAXED, __HIP_MEMORY_SCOPE_AGENT) < target)
    __builtin_amdgcn_s_sleep(1);
}
__device__ __forceinline__ void async_cp16(const void* g, void* l){
  __builtin_amdgcn_global_load_lds((const __attribute__((address_space(1))) u32*)g,
                                   (__attribute__((address_space(3))) u32*)l, 16, 0, 0);
}
__device__ __forceinline__ bf16x8 plain_ld16(const u16* p){ return *(const bf16x8*)p; }
__device__ __forceinline__ void ring_st16(u16* p, uint4 v){
  u64 lo = ((u64)v.y << 32) | v.x;
  u64 hi = ((u64)v.w << 32) | v.z;
  __hip_atomic_store((u64*)p,     lo, __ATOMIC_RELAXED, __HIP_MEMORY_SCOPE_AGENT);
  __hip_atomic_store(((u64*)p)+1, hi, __ATOMIC_RELAXED, __HIP_MEMORY_SCOPE_AGENT);
}

// ---------------- weight packing: B-operand fragment layout ------------------
// dst[((kc*128+ng)*64+ln)*8+j] = U[kc*32 + (ln>>4)*8 + j][ng*16 + (ln&15)]
__global__ void pack_w_kernel(const float* __restrict__ U1, const float* __restrict__ W2,
                              const float* __restrict__ U2, u16* __restrict__ U1p,
                              u16* __restrict__ UW2p)
{
  int idx = blockIdx.x*256 + threadIdx.x;
  int ln = idx & 63;
  int q8 = ((ln >> 4) << 3);
  int cl = ln & 15;
  if (idx < 16*128*64) {
    int kc = idx >> 13, ng = (idx >> 6) & 127;
    int row0 = kc*32 + q8, col = ng*16 + cl;
    u16* d = U1p + (size_t)idx*8;
    #pragma unroll
    for (int j=0;j<8;j++) d[j] = f2bf(U1[(size_t)(row0+j)*2048 + col]);
  } else {
    int i2 = idx - 16*128*64;
    if (i2 >= 32*128*64) return;
    int kc = i2 >> 13, ng = (i2 >> 6) & 127;
    int row0 = kc*32 + q8, col = ng*16 + cl;
    u16* d = UW2p + (size_t)i2*8;
    #pragma unroll
    for (int j=0;j<8;j++){
      int r = row0 + j;
      float v = (r < 512) ? W2[(size_t)r*2048 + col] : U2[(size_t)(r-512)*2048 + col];
      d[j] = f2bf(v);
    }
  }
}

__global__ void init_kernel(float* __restrict__ out, const float* __restrict__ fcb,
                            int* __restrict__ flags)
{
  int i = blockIdx.x*256 + threadIdx.x;
  if (i < 2048) flags[i] = 0;
  if (i < B_*T_) out[i] = fcb[0];
}

// ================================ v9 =========================================
// v7 partition + sync discipline, with the per-step serial chain shortened:
//  - L2 split-spin: W2 x h1[t] half (kc 0..15) runs after only the done1 spin
//    (h1 ready early -- L1 leads by up to 8 steps); done2 spin + 2nd inv sits
//    between the halves, so the h2 self-recurrence path is detect + 16 kc only.
//  - FC reduce/atomics moved AFTER the release RMW (register-only, off-path).
//  - inp prefetched into VGPRs before the spins (L1).
// L1: blk 0..127:   bi = blk&7 (8 cohorts x 64 rows), hj = blk>>3 (16 x 32 cols)
// L2: blk 128..255: bi2 = blk2&3 (4 cohorts x 128 rows), hj = blk2>>2 (32 x 16 cols)

__device__ void run_l1_v9(char* smem, int blk, const float* __restrict__ inp,
                          const float* __restrict__ W1, const float* __restrict__ V,
                          const float* __restrict__ bias, char* __restrict__ ws)
{
  u16*  Bl   = (u16*)smem;                        // [16kc][8ngl][512]
  u16*  hlds = (u16*)(smem + 131072);             // 64 x 40
  float* wlds = (float*)(smem + 131072 + 6144);   // 4*32*6
  constexpr int RS = 40;
  const int tid = threadIdx.x, w = tid>>6, ln = tid&63, col = ln&15, quad = ln>>4;
  const int bi = blk & 7, hj = blk >> 3, h0 = hj*32, bg = bi*4 + w;

  const u16* Upak = (const u16*)(ws + OFF_U1P);
  const u16* H1r  = (const u16*)(ws + OFF_H1);
  u16* Hw = (u16*)(ws + OFF_H1);
  int* done1 = (int*)(ws + OFF_FLAGS) + bi*FSTRIDE;
  int* done2 = (int*)(ws + OFF_FLAGS) + 1024 + (bi>>1)*FSTRIDE;

  // stage all of B once (32 pieces/wave x 1KB)
  #pragma unroll
  for (int p=0;p<32;p++){
    int pid = w*32 + p, kc = pid>>3, ngl = pid&7;
    int ng = (ngl>>1)*32 + hj*2 + (ngl&1);
    async_cp16(Upak + ((size_t)(kc*128+ng)*64 + ln)*8, Bl + (size_t)pid*512);
  }
  for (int idx=tid; idx<4*32*6; idx+=256){
    int gate = idx/192, rem = idx%192, hcol = rem/6, k = rem%6;
    int gcol = gate*512 + h0 + hcol;
    wlds[idx] = (k==0)? bias[gcol] : (k<=4 ? V[(size_t)(k-1)*2048 + gcol] : W1[gcol]);
  }

  float c[8];
  #pragma unroll
  for (int i=0;i<8;i++) c[i] = 0.f;
  const f32x4 vzero = {0.f,0.f,0.f,0.f};

  for (int t=0; t<T_; t++){
    // prefetch inp for this step BEFORE the spin (VGPRs survive the inv)
    float pin[4][5];
    #pragma unroll
    for (int r=0;r<4;r++){
      const float* ip = inp + ((size_t)(bi*64 + w*16 + quad*4 + r)*T_ + t)*5;
      #pragma unroll
      for (int k=0;k<5;k++) pin[r][k] = ip[k];
    }
    if (tid==0){
      if (t>0)      spin_ge(done1, 16*t);             // cohort: h1[t-1] full-K ready
      if (t>=NRING) spin_ge(done2, 32*(t-NRING+1));   // ring back-pressure
      __builtin_amdgcn_fence(__ATOMIC_ACQUIRE, "agent");  // one buffer_inv/step
    }
    __syncthreads();   // barrier 1 (drains B-stage at t=0; broadcasts inv)

    f32x4 acc[8];
    #pragma unroll
    for (int i=0;i<8;i++) acc[i] = vzero;

    if (t > 0){
      const u16* ab = H1r + (size_t)((t-1)&7)*H_SLOT + (size_t)bg*16*512 + (size_t)ln*8;
      bf16x8 aw[8];
      #pragma unroll
      for (int i=0;i<8;i++) aw[i] = plain_ld16(ab + (size_t)i*512);
      #pragma unroll
      for (int kc=0; kc<16; kc++){
        bf16x8 av = aw[kc&7];
        if (kc < 8) aw[kc&7] = plain_ld16(ab + (size_t)(kc+8)*512);
        const u16* bb = Bl + (size_t)kc*8*512 + (size_t)ln*8;
        #pragma unroll
        for (int ngl=0; ngl<8; ngl++)
          acc[ngl] = __builtin_amdgcn_mfma_f32_16x16x32_bf16(
              av, *(const bf16x8*)(bb + (size_t)ngl*512), acc[ngl], 0,0,0);
      }
    }

    // epilogue (wave-local)
    #pragma unroll
    for (int hg=0; hg<2; hg++){
      float wv[4][6];
      #pragma unroll
      for (int gate=0; gate<4; gate++){
        const float* wp = wlds + (size_t)(gate*32 + hg*16 + col)*6;
        #pragma unroll
        for (int k=0;k<6;k++) wv[gate][k] = wp[k];
      }
      #pragma unroll
      for (int r=0;r<4;r++){
        float gv[4];
        #pragma unroll
        for (int gate=0; gate<4; gate++){
          gv[gate] = acc[gate*2+hg][r] + wv[gate][0]
                   + pin[r][0]*wv[gate][1] + pin[r][1]*wv[gate][2]
                   + pin[r][2]*wv[gate][3] + pin[r][3]*wv[gate][4]
                   + pin[r][4]*wv[gate][5];
        }
        float ig=sigm_f(gv[0]), fg=sigm_f(gv[1]), gg=tanh_ff(gv[2]), og=sigm_f(gv[3]);
        float cn = fg*c[hg*4+r] + ig*gg;
        c[hg*4+r] = cn;
        hlds[(size_t)(w*16 + quad*4 + r)*RS + hg*16 + col] = f2bf(og*tanh_ff(cn));
      }
    }
    // pack: SAME-WAVE transpose via hlds (no barrier needed before read)
    {
      uint4 v = *(const uint4*)&hlds[(size_t)(w*16 + (ln&15))*RS + (ln>>4)*8];
      ring_st16(Hw + (size_t)(t&7)*H_SLOT + ((size_t)(bg*16 + hj)*64 + ln)*8, v);
    }
    __syncthreads();   // barrier 2: all waves' pack stores drained (vmcnt(0))
    if (tid==0){
      __builtin_amdgcn_fence(__ATOMIC_RELEASE, "workgroup");
      __hip_atomic_fetch_add(done1, 1, __ATOMIC_RELAXED, __HIP_MEMORY_SCOPE_AGENT);
    }
  }
}

__device__ void run_l2_v9(char* smem, int blk2, const float* __restrict__ inp,
                          const float* __restrict__ V, const float* __restrict__ bias,
                          const float* __restrict__ fcw, char* __restrict__ ws,
                          float* __restrict__ out)
{
  u16*  Bl   = (u16*)smem;                        // [32kc][4ngl][512]; kc<16=W2, >=16=U2
  u16*  hlds = (u16*)(smem + 131072);             // 128 x 24
  float* wlds = (float*)(smem + 131072 + 6144);   // 4*16*6
  constexpr int RS = 24;
  const int tid = threadIdx.x, w = tid>>6, ln = tid&63, col = ln&15, quad = ln>>4;
  const int bi2 = blk2 & 3, hj = blk2 >> 2, h0 = hj*16;
  const int bgA = bi2*8 + w, bgB = bgA + 4;

  const u16* Upak = (const u16*)(ws + OFF_UW2P);
  const u16* H1r  = (const u16*)(ws + OFF_H1);
  const u16* H2r  = (const u16*)(ws + OFF_H2);
  u16* Hw = (u16*)(ws + OFF_H2);
  int* flags = (int*)(ws + OFF_FLAGS);
  int* d1a = flags + (2*bi2)*FSTRIDE;
  int* d1b = flags + (2*bi2+1)*FSTRIDE;
  int* done2 = flags + 1024 + bi2*FSTRIDE;

  #pragma unroll
  for (int p=0;p<32;p++){
    int pid = w*32 + p, kc = pid>>2, ngl = pid&3;
    int ng = ngl*32 + hj;
    async_cp16(Upak + ((size_t)(kc*128+ng)*64 + ln)*8, Bl + (size_t)pid*512);
  }
  for (int idx=tid; idx<4*16*6; idx+=256){
    int gate = idx/96, rem = idx%96, hcol = rem/6, k = rem%6;
    int gcol = gate*512 + h0 + hcol;
    wlds[idx] = (k==0)? bias[gcol] : (k<=4 ? V[(size_t)(k-1)*2048 + gcol] : 0.f);
  }
  const float fcwr = fcw[h0 + col];

  float c[8];
  #pragma unroll
  for (int i2_=0;i2_<8;i2_++) c[i2_] = 0.f;
  const f32x4 vzero = {0.f,0.f,0.f,0.f};

  for (int t=0; t<T_; t++){
    // ---- phase 1: W2 x h1[t] (h1 ready early; off the self-recurrence path) --
    if (tid==0){
      spin_ge(d1a, 16*(t+1));                 // h1[t] ready (both L1 bi halves)
      spin_ge(d1b, 16*(t+1));
      __builtin_amdgcn_fence(__ATOMIC_ACQUIRE, "agent");
    }
    __syncthreads();   // barrier 1 (drains B-stage at t=0)

    f32x4 accA[4], accB[4];
    #pragma unroll
    for (int q=0;q<4;q++){ accA[q] = vzero; accB[q] = vzero; }

    {
      const u16* A1 = H1r + (size_t)(t&7)*H_SLOT;
      bf16x8 awA[8], awB[8];
      #pragma unroll
      for (int i=0;i<8;i++){
        awA[i] = plain_ld16(A1 + ((size_t)bgA*16 + i)*512 + (size_t)ln*8);
        awB[i] = plain_ld16(A1 + ((size_t)bgB*16 + i)*512 + (size_t)ln*8);
      }
      #pragma unroll
      for (int kc=0; kc<16; kc++){
        bf16x8 avA = awA[kc&7], avB = awB[kc&7];
        if (kc < 8){
          awA[kc&7] = plain_ld16(A1 + ((size_t)bgA*16 + kc+8)*512 + (size_t)ln*8);
          awB[kc&7] = plain_ld16(A1 + ((size_t)bgB*16 + kc+8)*512 + (size_t)ln*8);
        }
        const u16* bb = Bl + (size_t)kc*4*512 + (size_t)ln*8;
        #pragma unroll
        for (int g=0; g<4; g++){
          bf16x8 bf = *(const bf16x8*)(bb + (size_t)g*512);
          accA[g] = __builtin_amdgcn_mfma_f32_16x16x32_bf16(avA, bf, accA[g], 0,0,0);
          accB[g] = __builtin_amdgcn_mfma_f32_16x16x32_bf16(avB, bf, accB[g], 0,0,0);
        }
      }
    }

    // ---- phase 2: U2 x h2[t-1] (the recurrence critical path: detect + 16kc) --
    if (t > 0){
      if (tid==0){
        spin_ge(done2, 32*t);
        __builtin_amdgcn_fence(__ATOMIC_ACQUIRE, "agent");  // 2nd inv: h2 freshness
      }
      __syncthreads();   // barrier 2
      const u16* A2 = H2r + (size_t)((t-1)&1)*H_SLOT;
      bf16x8 awA[8], awB[8];
      #pragma unroll
      for (int i=0;i<8;i++){
        awA[i] = plain_ld16(A2 + ((size_t)bgA*16 + i)*512 + (size_t)ln*8);
        awB[i] = plain_ld16(A2 + ((size_t)bgB*16 + i)*512 + (size_t)ln*8);
      }
      #pragma unroll
      for (int kc=0; kc<16; kc++){
        bf16x8 avA = awA[kc&7], avB = awB[kc&7];
        if (kc < 8){
          awA[kc&7] = plain_ld16(A2 + ((size_t)bgA*16 + kc+8)*512 + (size_t)ln*8);
          awB[kc&7] = plain_ld16(A2 + ((size_t)bgB*16 + kc+8)*512 + (size_t)ln*8);
        }
        const u16* bb = Bl + (size_t)(16+kc)*4*512 + (size_t)ln*8;
        #pragma unroll
        for (int g=0; g<4; g++){
          bf16x8 bf = *(const bf16x8*)(bb + (size_t)g*512);
          accA[g] = __builtin_amdgcn_mfma_f32_16x16x32_bf16(avA, bf, accA[g], 0,0,0);
          accB[g] = __builtin_amdgcn_mfma_f32_16x16x32_bf16(avB, bf, accB[g], 0,0,0);
        }
      }
    }

    // ---- epilogue ------------------------------------------------------------
    float wv[4][5];
    #pragma unroll
    for (int gate=0; gate<4; gate++){
      const float* wp = wlds + (size_t)(gate*16 + col)*6;
      #pragma unroll
      for (int k=0;k<5;k++) wv[gate][k] = wp[k];
    }
    float fcp[2][4];
    #pragma unroll
    for (int sel=0; sel<2; sel++){
      const f32x4* ac = sel ? accB : accA;
      #pragma unroll
      for (int r=0;r<4;r++){
        const float* ip = inp + ((size_t)(bi2*128 + sel*64 + w*16 + quad*4 + r)*T_ + t)*5;
        float i0=ip[0], i1=ip[1], i2=ip[2], i3=ip[3];
        float gv[4];
        #pragma unroll
        for (int gate=0; gate<4; gate++){
          gv[gate] = ac[gate][r] + wv[gate][0]
                   + i0*wv[gate][1] + i1*wv[gate][2] + i2*wv[gate][3] + i3*wv[gate][4];
        }
        float ig=sigm_f(gv[0]), fg=sigm_f(gv[1]), gg=tanh_ff(gv[2]), og=sigm_f(gv[3]);
        float cn = fg*c[sel*4+r] + ig*gg;
        c[sel*4+r] = cn;
        float h = og*tanh_ff(cn);
        fcp[sel][r] = h*fcwr;
        hlds[(size_t)(sel*64 + w*16 + quad*4 + r)*RS + col] = f2bf(h);
      }
    }
    // pack FIRST (same-wave transpose), then drain+release; FC moves off-path.
    {
      int sel = ln>>5, ch = (ln>>4)&1, m = ln&15;
      uint4 v = *(const uint4*)&hlds[(size_t)(sel*64 + w*16 + m)*RS + ch*8];
      int lp = ((hj&1)*2 + ch)*16 + m;
      int bgx = bi2*8 + sel*4 + w;
      ring_st16(Hw + (size_t)(t&1)*H_SLOT + (((size_t)bgx*16 + (hj>>1))*64 + lp)*8, v);
    }
    __syncthreads();   // barrier 3: pack stores drained
    if (tid==0){
      __builtin_amdgcn_fence(__ATOMIC_RELEASE, "workgroup");
      __hip_atomic_fetch_add(done2, 1, __ATOMIC_RELAXED, __HIP_MEMORY_SCOPE_AGENT);
    }
    // FC reduce + atomics AFTER the release (register-only; overlaps next spin)
    #pragma unroll
    for (int sel=0; sel<2; sel++){
      #pragma unroll
      for (int r=0;r<4;r++){
        float v = fcp[sel][r];
        #pragma unroll
        for (int m=1;m<16;m<<=1) v += __shfl_xor(v, m, 16);
        if (col == 0)
          atomicAdd(&out[(size_t)(bi2*128 + sel*64 + w*16 + quad*4 + r)*T_ + t], v);
      }
    }
  }
}

__global__ void __launch_bounds__(256, 1)
lstm_main_v9(const float* __restrict__ inp, const float* __restrict__ W1,
             const float* __restrict__ V1, const float* __restrict__ b1,
             const float* __restrict__ V2, const float* __restrict__ b2,
             const float* __restrict__ fcw, char* __restrict__ ws, float* __restrict__ out)
{
  extern __shared__ char smem[];
  int blk = blockIdx.x;
  if (blk < 128) run_l1_v9(smem, blk, inp, W1, V1, b1, ws);
  else           run_l2_v9(smem, blk-128, inp, V2, b2, fcw, ws, out);
}

extern "C" void kernel_launch(void* const* d_in, const int* in_sizes, int n_in,
                              void* d_out, int out_size, void* d_ws, size_t ws_size,
                              hipStream_t stream) {
  const float* inp = (const float*)d_in[0];
  const float* W1  = (const float*)d_in[1];
  const float* U1  = (const float*)d_in[2];
  const float* V1  = (const float*)d_in[3];
  const float* b1  = (const float*)d_in[4];
  const float* W2  = (const float*)d_in[5];
  const float* U2  = (const float*)d_in[6];
  const float* V2  = (const float*)d_in[7];
  const float* b2  = (const float*)d_in[8];
  const float* fcw = (const float*)d_in[9];
  const float* fcb = (const float*)d_in[10];
  char* ws = (char*)d_ws;
  float* out = (float*)d_out;

  pack_w_kernel<<<1536, 256, 0, stream>>>(U1, W2, U2,
      (u16*)(ws + OFF_U1P), (u16*)(ws + OFF_UW2P));
  init_kernel<<<(B_*T_ + 255)/256, 256, 0, stream>>>(out, fcb, (int*)(ws + OFF_FLAGS));

  // 256 blocks x 140KB dynamic LDS (proven on this device in r6/r7) ->
  // 1 block/CU, all co-resident, spin-flag sync safe.
  (void)hipFuncSetAttribute((const void*)lstm_main_v9,
                            hipFuncAttributeMaxDynamicSharedMemorySize, SMEM_V9);
  lstm_main_v9<<<256, 256, SMEM_V9, stream>>>(inp, W1, V1, b1, V2, b2, fcw, ws, out);
}